// Round 1
// 371.877 us; speedup vs baseline: 1.0017x; 1.0017x over previous
//
#include <hip/hip_runtime.h>

// Problem shapes (static per reference):
//   last_hidden_state: (16, 4096, 1024) fp32   -> d_in[0]
//   sentence_mask:     (16, 4096) int32 (0..31)-> d_in[1]  (JAX x64 off => int32)
//   num_sents = 32                             -> d_in[2] (unused, static)
// Outputs (flat fp32 in d_out):
//   [0 .. 524287]       sentence_embeddings (16, 32, 1024)
//   [524288 .. 524319]  unique_sents = 0..31 (as float)
//
// Strategy (v2): gather-by-sentence. The old accum_kernel's per-thread
// LDS read-modify-write chain (acc[smask[i]][tid] += x) serialized at
// ~130 cyc/element and throttled HBM to ~0.8 TB/s. Instead:
//   prep_kernel:   per batch, histogram mask -> prefix -> row-index lists
//                  (perm) grouped by sentence, in workspace.
//   gather_kernel: one block per (batch, sentence, column-half); streams
//                  its rows with float4 loads into register accumulators
//                  (independent iterations -> full MLP), writes out/count
//                  exactly once. No atomics, no memset, no finalize.

#define BATCH   16
#define SEQ     4096
#define HIDDEN  1024
#define NSENT   32
#define EMB_ELEMS (BATCH * NSENT * HIDDEN)   // 524288

#define CHUNK2   512                  // hidden columns per gather block
#define NCHUNK2  (HIDDEN / CHUNK2)    // 2
#define GTHREADS 128                  // threads per gather block (x4 floats = 512 cols)

// ---------------------------------------------------------------------------
// Per-batch: histogram -> exclusive prefix -> scatter row indices grouped by
// sentence. perm[b*SEQ + pref[s] .. ] holds the row ids of sentence s.
// offs[b*33 + s] = exclusive prefix (offs[..+32] = 4096).
// Also emits the unique_sents tail of d_out (block 0).
__global__ __launch_bounds__(256) void prep_kernel(const int* __restrict__ mask,
                                                   int* __restrict__ perm,
                                                   int* __restrict__ offs,
                                                   float* __restrict__ out) {
    __shared__ int sm[SEQ];          // 16 KB: cached sentence ids
    __shared__ int cnt[NSENT];
    __shared__ int pref[NSENT];
    __shared__ int cursor[NSENT];

    const int b   = blockIdx.x;
    const int tid = threadIdx.x;

    if (tid < NSENT) cnt[tid] = 0;
    __syncthreads();

    #pragma unroll
    for (int i = tid; i < SEQ; i += 256) {
        const int s = mask[b * SEQ + i] & (NSENT - 1);
        sm[i] = s;
        atomicAdd(&cnt[s], 1);
    }
    __syncthreads();

    if (tid == 0) {
        int run = 0;
        #pragma unroll
        for (int s = 0; s < NSENT; ++s) { pref[s] = run; run += cnt[s]; }
    }
    __syncthreads();

    if (tid < NSENT) {
        cursor[tid] = pref[tid];
        offs[b * (NSENT + 1) + tid] = pref[tid];
    }
    if (tid == 0) offs[b * (NSENT + 1) + NSENT] = SEQ;
    if (b == 0 && tid < NSENT) out[EMB_ELEMS + tid] = (float)tid;
    __syncthreads();

    // Scatter row ids into sentence-grouped order. Order within a sentence is
    // nondeterministic (LDS atomic cursors) — FP sum order varies, fine at
    // the harness tolerance (old kernel's global atomics were the same).
    for (int i = tid; i < SEQ; i += 256) {
        const int s   = sm[i];
        const int pos = atomicAdd(&cursor[s], 1);
        perm[b * SEQ + pos] = i;
    }
}

// ---------------------------------------------------------------------------
// Block = (batch b, sentence s, column-half). Stage the (variable-length) row
// list into LDS, then stream rows: one float4 per lane per row, accumulate in
// registers. Iterations are independent -> loads pipeline 8 deep (unroll),
// ~32 KB in flight per CU at 4 blocks/CU, well past the ~9 KB needed to
// cover HBM latency. Single write of sum/count at the end.
__global__ __launch_bounds__(GTHREADS) void gather_kernel(const float* __restrict__ x,
                                                          const int* __restrict__ perm,
                                                          const int* __restrict__ offs,
                                                          float* __restrict__ out) {
    __shared__ int sidx[SEQ];        // 16 KB worst case (one sentence owns all rows)

    const int tid   = threadIdx.x;
    const int blk   = blockIdx.x;
    const int chunk = blk & (NCHUNK2 - 1);
    const int s     = (blk >> 1) & (NSENT - 1);
    const int b     = blk >> 6;                  // 64 blocks per batch

    const int base  = b * (NSENT + 1) + s;
    const int start = offs[base];
    const int n     = offs[base + 1] - start;

    for (int j = tid; j < n; j += GTHREADS)
        sidx[j] = perm[b * SEQ + start + j];
    __syncthreads();

    const int c0 = chunk * CHUNK2 + tid * 4;
    const float* xb = x + (size_t)b * SEQ * HIDDEN + c0;

    float ax = 0.f, ay = 0.f, az = 0.f, aw = 0.f;
    #pragma unroll 8
    for (int k = 0; k < n; ++k) {
        const float4 v = *(const float4*)(xb + (size_t)sidx[k] * HIDDEN);
        ax += v.x; ay += v.y; az += v.z; aw += v.w;
    }

    const float inv = 1.0f / (float)n;
    float4 r; r.x = ax * inv; r.y = ay * inv; r.z = az * inv; r.w = aw * inv;
    *(float4*)(out + (size_t)(b * NSENT + s) * HIDDEN + c0) = r;
}

// ---------------------------------------------------------------------------
extern "C" void kernel_launch(void* const* d_in, const int* in_sizes, int n_in,
                              void* d_out, int out_size, void* d_ws, size_t ws_size,
                              hipStream_t stream) {
    const float* x    = (const float*)d_in[0];
    const int*   mask = (const int*)d_in[1];
    float*       out  = (float*)d_out;

    int* perm = (int*)d_ws;                    // 16*4096 ints = 256 KB
    int* offs = perm + BATCH * SEQ;            // 16*33 ints

    prep_kernel<<<BATCH, 256, 0, stream>>>(mask, perm, offs, out);
    gather_kernel<<<BATCH * NSENT * NCHUNK2, GTHREADS, 0, stream>>>(x, perm, offs, out);
}